// Round 15
// baseline (122.261 us; speedup 1.0000x reference)
//
#include <hip/hip_runtime.h>
#include <hip/hip_bf16.h>
#include <math.h>

// Problem constants
#define BATCH 8
#define T 2048
#define E 1024
#define HD 64
#define BT (BATCH * T)  // 16384

typedef __bf16 bf16_t;
typedef bf16_t bf16x4 __attribute__((ext_vector_type(4)));
typedef bf16_t bf16x8 __attribute__((ext_vector_type(8)));
typedef float f32x4 __attribute__((ext_vector_type(4)));

#define MFMA(a, b, c) __builtin_amdgcn_mfma_f32_16x16x32_bf16((a), (b), (c), 0, 0, 0)

// q scale folded into Wq at prep; softmax in exp2 domain (no-max: scores
// sigma~1.44, f32 exp2 overflows at 127 ~ 88 sigma -- unreachable).
#define QSCALE (0.125f * 1.44269504088896340736f)

// Tiled layout for all MFMA operands: idx(r,c) over [R][C] =
//   (r>>4)*(16*C) + (c>>3)*128 + (r&15)*8 + (c&7)
// => a wave fragment load is ONE contiguous 1KB read: base + c0*16 + lane*8.

// ---------------------------------------------------------------------------
// Kernel 0: prep weights into tiled WT[192 n][1024 k] = W[k][n] (*QSCALE for q).
// ---------------------------------------------------------------------------
__global__ __launch_bounds__(256) void prep_w(const float* __restrict__ Wq,
                                              const float* __restrict__ Wk,
                                              const float* __restrict__ Wv,
                                              bf16_t* __restrict__ WTt) {
    const int nt  = blockIdx.x >> 3;          // 0..11
    const int kc0 = (blockIdx.x & 7) * 128;
    const int tid = threadIdx.x;
    const int l16 = tid & 15;
    const int k8  = (kc0 >> 3) + (tid >> 4);  // 0..127
    const int n   = nt * 16 + l16;
    const int m   = n >> 6;                   // block-uniform: 0=q,1=k,2=v
    const int col = n & 63;
    const float* W = (m == 0) ? Wq : (m == 1) ? Wk : Wv;
    const float scale = (m == 0) ? QSCALE : 1.0f;
    bf16x8 o;
#pragma unroll
    for (int j = 0; j < 8; j++) {
        o[j] = (bf16_t)(W[(size_t)(k8 * 8 + j) * HD + col] * scale);
    }
    *reinterpret_cast<bf16x8*>(WTt + (size_t)nt * 16384 + k8 * 128 + l16 * 8) = o;
}

// ---------------------------------------------------------------------------
// Kernel 1: QKV projection — R15: glds-f32 burst stage + K-split compute.
// [Measured record: R9's glds burst is the ONLY staging that hit full HBM
// rate (~5us per 32MB generation); reg-path stage (R10/R11/R14) is slower
// (VGPR round-trip + per-round vmcnt stalls). R9's weakness was B-traffic
// ~ blockcount x 384KB (1024 blocks = 393MB). R15 = R9 staging + R11
// K-split compute at 512 blocks: B = 197MB, stage at full rate.]
// Grid 512 x 512 thr (8 waves), block = 32 rows. LDS f32 [32][1024] =
// 128 KB -> 1 block/CU, two generations. Stage: 128 glds-1KB instrs,
// 16/wave back-to-back (128 KB/CU in flight; DMA, can't be sunk);
// swizzle (R9-verified): lane fetches global segment (lane^(r&7)), LDS
// linear; read XORs the slot index. Compute: wk=w>>2 K-half (B read once
// per block), wc=w&3 col tiles; A cvt f32->bf16 at fragment read (R9-
// verified). Merge + epilogue = R14 verbatim (passed).
// ---------------------------------------------------------------------------
__global__ __launch_bounds__(512, 2) void qkv_proj(
    const float* __restrict__ x,     // [BT][E] f32
    const bf16_t* __restrict__ WTt,  // tiled [192][E]
    bf16_t* __restrict__ qt,         // tiled [BT][HD] (scaled)
    bf16_t* __restrict__ kt,         // tiled [BT][HD]
    bf16_t* __restrict__ vt)         // tiled per batch [HD][T]
{
    __shared__ __align__(16) float xlds[32][1024];   // 128 KB f32, linear

    const int tid  = threadIdx.x;
    const int w    = tid >> 6;           // wave 0..7
    const int lane = tid & 63;
    const int l16  = lane & 15;
    const int quad = lane >> 4;
    const int wk   = w >> 2;             // K half: [wk*512, +512)
    const int wc   = w & 3;              // col tiles 3wc..3wc+2
    const int rowbase0 = blockIdx.x * 32;

    // ---- glds burst stage: wave w -> rows 4w..4w+3, 4 quarter-rows each.
    // instr (r,qq): 64 lanes -> LDS &xlds[r][qq*256] + lane*16B (linear);
    // lane fetches global segment qq*64 + (lane ^ (r&7)) of row r. ----
#pragma unroll
    for (int i = 0; i < 16; i++) {
        const int gi = w * 16 + i;       // 0..127
        const int r  = gi >> 2;          // 0..31
        const int qq = gi & 3;
        const float* gsrc = x + (size_t)(rowbase0 + r) * E + qq * 256 +
                            ((lane ^ (r & 7)) * 4);
        __builtin_amdgcn_global_load_lds(
            (const __attribute__((address_space(1))) unsigned int*)gsrc,
            (__attribute__((address_space(3))) unsigned int*)&xlds[r][qq * 256],
            16, 0, 0);
    }
    __syncthreads();   // strip resident

    // ---- compute: 8 kc-iters over own K-half; B read once per block ----
    const bf16_t* Bb = WTt + (size_t)(wc * 3) * 16384 + lane * 8;
    f32x4 acc[2][3] = {};

    for (int kc8 = 0; kc8 < 8; kc8++) {
        const int kk = wk * 512 + kc8 * 64;
        bf16x8 bf[2][3];
#pragma unroll
        for (int ks = 0; ks < 2; ks++)
#pragma unroll
            for (int tc = 0; tc < 3; tc++)
                bf[ks][tc] = *reinterpret_cast<const bf16x8*>(
                    Bb + (size_t)tc * 16384 + (kk + ks * 32) * 16);

#pragma unroll
        for (int g = 0; g < 2; g++) {
            const int row = g * 16 + l16;
            const int rx  = row & 7;
            const int c0  = (kk >> 2) + quad * 2;     // 16B-slot index
            const f32x4 va0 = *reinterpret_cast<const f32x4*>(&xlds[row][((c0)     ^ rx) * 4]);
            const f32x4 vb0 = *reinterpret_cast<const f32x4*>(&xlds[row][((c0 + 1) ^ rx) * 4]);
            const f32x4 va1 = *reinterpret_cast<const f32x4*>(&xlds[row][((c0 + 8) ^ rx) * 4]);
            const f32x4 vb1 = *reinterpret_cast<const f32x4*>(&xlds[row][((c0 + 9) ^ rx) * 4]);
            bf16x8 a0, a1;
#pragma unroll
            for (int u = 0; u < 4; u++) {
                a0[u]     = (bf16_t)va0[u];
                a0[4 + u] = (bf16_t)vb0[u];
                a1[u]     = (bf16_t)va1[u];
                a1[4 + u] = (bf16_t)vb1[u];
            }
#pragma unroll
            for (int tc = 0; tc < 3; tc++) acc[g][tc] = MFMA(a0, bf[0][tc], acc[g][tc]);
#pragma unroll
            for (int tc = 0; tc < 3; tc++) acc[g][tc] = MFMA(a1, bf[1][tc], acc[g][tc]);
        }
    }

    // ---- merge K-half partials via LDS (xlds reusable after sync) ----
    __syncthreads();
    float* pbuf = reinterpret_cast<float*>(&xlds[0][0]);   // 24 KB used
    if (wk == 1) {
#pragma unroll
        for (int g = 0; g < 2; g++)
#pragma unroll
            for (int tc = 0; tc < 3; tc++) {
                const int idx = (((wc * 2 + g) * 3) + tc) * 256 + lane * 4;
                *reinterpret_cast<f32x4*>(pbuf + idx) = acc[g][tc];
            }
    }
    __syncthreads();
    if (wk == 0) {
#pragma unroll
        for (int g = 0; g < 2; g++)
#pragma unroll
            for (int tc = 0; tc < 3; tc++) {
                const int idx = (((wc * 2 + g) * 3) + tc) * 256 + lane * 4;
                acc[g][tc] += *reinterpret_cast<const f32x4*>(pbuf + idx);
            }

        // ---- epilogue (R14-verified mapping), per row group ----
#pragma unroll
        for (int g = 0; g < 2; g++) {
            const int rowbase = rowbase0 + g * 16;
#pragma unroll
            for (int tc = 0; tc < 3; tc++) {
                const int n0  = wc * 48 + tc * 16;
                const int m   = n0 >> 6;     // wave-uniform per tc: 0=q,1=k,2=v
                const int tcg = (n0 & 63) >> 4;
                if (m < 2) {
                    bf16_t* dst = (m == 0) ? qt : kt;
                    const size_t o0 = (size_t)(rowbase >> 4) * 1024 +
                                      (size_t)(tcg * 2 + (l16 >> 3)) * 128 + (l16 & 7);
#pragma unroll
                    for (int r = 0; r < 4; r++) {
                        dst[o0 + (quad * 4 + r) * 8] = (bf16_t)acc[g][tc][r];
                    }
                } else {
                    const int b_    = rowbase >> 11;
                    const int tbase = rowbase & (T - 1);
                    const size_t o0 = (size_t)b_ * 131072 +
                                      (size_t)((tbase >> 3) + (quad >> 1)) * 128 +
                                      l16 * 8 + (quad & 1) * 4 + (size_t)tcg * 32768;
                    bf16x4 pv;
#pragma unroll
                    for (int r = 0; r < 4; r++) pv[r] = (bf16_t)acc[g][tc][r];
                    *reinterpret_cast<bf16x4*>(vt + o0) = pv;
                }
            }
        }
    }
}

// ---------------------------------------------------------------------------
// Kernel 2: causal flash attention — R13 supertile/task-queue version,
// byte-identical (passed).
// ---------------------------------------------------------------------------
__global__ __launch_bounds__(512, 2) void attn(
    const bf16_t* __restrict__ qtl,  // tiled [BT][HD], pre-scaled
    const bf16_t* __restrict__ ktl,  // tiled [BT][HD]
    const bf16_t* __restrict__ vtl,  // tiled per batch [HD][T]
    float* __restrict__ out)         // [BT][HD] f32 row-major
{
    __shared__ __align__(16) bf16_t plds[8][2][16][40];
    __shared__ float opart[8][16][66];
    __shared__ float lpart[8][16];

    const int tid  = threadIdx.x;
    const int wave = tid >> 6;
    const int lane = tid & 63;
    const int l16  = lane & 15;
    const int quad = lane >> 4;

    const int b  = blockIdx.x >> 5;      // 0..7
    const int pp = blockIdx.x & 31;      // 0..31
    const int rbA = pp * 32;             // supertile A rows
    const int rbB = (63 - pp) * 32;      // supertile B rows
    const int nchA = pp + 1;             // chunks for A; B has 64-pp; total 65

    const bf16_t* Kb = ktl + (size_t)b * T * 64 + lane * 8;
    const bf16_t* Vb = vtl + (size_t)b * 131072 + lane * 8;
    const bf16_t* QbA = qtl + (size_t)((b * T + rbA) >> 4) * 1024 + lane * 8;
    const bf16_t* QbB = qtl + (size_t)((b * T + rbB) >> 4) * 1024 + lane * 8;

    // Q fragments: per supertile, 2 subtiles x {K0-31, K32-63}
    const bf16x8 qA0l = *reinterpret_cast<const bf16x8*>(QbA);
    const bf16x8 qA0h = *reinterpret_cast<const bf16x8*>(QbA + 512);
    const bf16x8 qA1l = *reinterpret_cast<const bf16x8*>(QbA + 1024);
    const bf16x8 qA1h = *reinterpret_cast<const bf16x8*>(QbA + 1536);
    const bf16x8 qB0l = *reinterpret_cast<const bf16x8*>(QbB);
    const bf16x8 qB0h = *reinterpret_cast<const bf16x8*>(QbB + 512);
    const bf16x8 qB1l = *reinterpret_cast<const bf16x8*>(QbB + 1024);
    const bf16x8 qB1h = *reinterpret_cast<const bf16x8*>(QbB + 1536);

    f32x4 oA0[4] = {}, oA1[4] = {}, oB0[4] = {}, oB1[4] = {};
    f32x4 lrA0 = {}, lrA1 = {}, lrB0 = {}, lrB1 = {};

    // preload K for first task
    int k0;
    bf16x8 kfa0, kfb0, kfa1, kfb1;
    {
        const int tf = wave;
        const int cf = (tf < nchA) ? tf : tf - nchA;
        kfa0 = *reinterpret_cast<const bf16x8*>(Kb + cf * 32 * 64);
        kfb0 = *reinterpret_cast<const bf16x8*>(Kb + cf * 32 * 64 + 512);
        kfa1 = *reinterpret_cast<const bf16x8*>(Kb + cf * 32 * 64 + 1024);
        kfb1 = *reinterpret_cast<const bf16x8*>(Kb + cf * 32 * 64 + 1536);
    }

#define ATTN_STEP(QL0, QH0, QL1, QH1, RB_, O0, O1, LR0, LR1)                  \
    {                                                                         \
        f32x4 s0l = {}, s0h = {}, s1l = {}, s1h = {};                         \
        s0l = MFMA(QL0, kfa0, s0l);  s0l = MFMA(QH0, kfb0, s0l);              \
        s0h = MFMA(QL0, kfa1, s0h);  s0h = MFMA(QH0, kfb1, s0h);              \
        s1l = MFMA(QL1, kfa0, s1l);  s1l = MFMA(QH1, kfb0, s1l);              \
        s1h = MFMA(QL1, kfa1, s1h);  s1h = MFMA(QH1, kfb1, s1h);              \
        if (k0 + 31 > (RB_)) {                                                \
            const int row = (RB_) + quad * 4;                                 \
            _Pragma("unroll")                                                 \
            for (int r = 0; r < 4; r++) {                                     \
                if (k0 + l16 > row + r)      s0l[r] = -INFINITY;              \
                if (k0 + 16 + l16 > row + r) s0h[r] = -INFINITY;              \
            }                                                                 \
        }                                                                     \
        if (k0 + 31 > (RB_) + 16) {                                           \
            const int row = (RB_) + 16 + quad * 4;                            \
            _Pragma("unroll")                                                 \
            for (int r = 0; r < 4; r++) {                                     \
                if (k0 + l16 > row + r)      s1l[r] = -INFINITY;              \
                if (k0 + 16 + l16 > row + r) s1h[r] = -INFINITY;              \
            }                                                                 \
        }                                                                     \
        _Pragma("unroll")                                                     \
        for (int r = 0; r < 4; r++) {                                         \
            const float p00 = exp2f(s0l[r]);                                  \
            const float p01 = exp2f(s0h[r]);                                  \
            (LR0)[r] += p00 + p01;                                            \
            plds[wave][0][quad * 4 + r][l16]      = (bf16_t)p00;              \
            plds[wave][0][quad * 4 + r][16 + l16] = (bf16_t)p01;              \
            const float p10 = exp2f(s1l[r]);                                  \
            const float p11 = exp2f(s1h[r]);                                  \
            (LR1)[r] += p10 + p11;                                            \
            plds[wave][1][quad * 4 + r][l16]      = (bf16_t)p10;              \
            plds[wave][1][quad * 4 + r][16 + l16] = (bf16_t)p11;              \
        }                                                                     \
        const bf16x8 pf0 = *reinterpret_cast<const bf16x8*>(                  \
            &plds[wave][0][l16][quad * 8]);                                   \
        const bf16x8 pf1 = *reinterpret_cast<const bf16x8*>(                  \
            &plds[wave][1][l16][quad * 8]);                                   \
        (O0)[0] = MFMA(pf0, vf0, (O0)[0]);  (O1)[0] = MFMA(pf1, vf0, (O1)[0]);\
        (O0)[1] = MFMA(pf0, vf1, (O0)[1]);  (O1)[1] = MFMA(pf1, vf1, (O1)[1]);\
        (O0)[2] = MFMA(pf0, vf2, (O0)[2]);  (O1)[2] = MFMA(pf1, vf2, (O1)[2]);\
        (O0)[3] = MFMA(pf0, vf3, (O0)[3]);  (O1)[3] = MFMA(pf1, vf3, (O1)[3]);\
    }

    for (int task = wave; task < 65; task += 8) {
        const bool isA = task < nchA;
        const int  c   = isA ? task : task - nchA;
        k0 = c * 32;

        // V for this chunk first (consumed this iter)...
        const bf16x8 vf0 = *reinterpret_cast<const bf16x8*>(Vb + k0 * 16);
        const bf16x8 vf1 = *reinterpret_cast<const bf16x8*>(Vb + k0 * 16 + 32768);
        const bf16x8 vf2 = *reinterpret_cast<const bf16x8*>(Vb + k0 * 16 + 65536);
        const bf16x8 vf3 = *reinterpret_cast<const bf16x8*>(Vb + k0 * 16 + 98304);
        // ...then next-task K prefetch (newer: never drained by this iter)
        const int tn = (task + 8 < 65) ? task + 8 : task;
        const int cn = (tn < nchA) ? tn : tn - nchA;
        const int kn = cn * 32;
        const bf16x8 nkfa0 = *reinterpret_cast<const bf16x8*>(Kb + kn * 64);
        const bf16x8 nkfb0 = *reinterpret_cast<const bf16x8*>(Kb + kn * 64 + 512);
        const bf16x8 nkfa1 = *reinterpret_cast<const bf16x8*>(Kb + kn * 64 + 1024);
        const bf16x8 nkfb1 = *reinterpret_cast<const bf16x8*>(Kb + kn * 64 + 1536);

        if (isA) {
            ATTN_STEP(qA0l, qA0h, qA1l, qA1h, rbA, oA0, oA1, lrA0, lrA1)
        } else {
            ATTN_STEP(qB0l, qB0h, qB1l, qB1h, rbB, oB0, oB1, lrB0, lrB1)
        }

        kfa0 = nkfa0; kfb0 = nkfb0; kfa1 = nkfa1; kfb1 = nkfb1;
    }
#undef ATTN_STEP

    // ---- 4-stage deposit + merge (reuses opart/lpart each stage) ----
#define DEPOSIT_MERGE(OX, LRX, ROWBASE)                                       \
    {                                                                         \
        _Pragma("unroll")                                                     \
        for (int r = 0; r < 4; r++) {                                         \
            float l = (LRX)[r];                                               \
            l += __shfl_xor(l, 1); l += __shfl_xor(l, 2);                     \
            l += __shfl_xor(l, 4); l += __shfl_xor(l, 8);                     \
            if (l16 == 0) lpart[wave][quad * 4 + r] = l;                      \
            _Pragma("unroll")                                                 \
            for (int nb = 0; nb < 4; nb++)                                    \
                opart[wave][quad * 4 + r][nb * 16 + l16] = (OX)[nb][r];       \
        }                                                                     \
        __syncthreads();                                                      \
        {                                                                     \
            const int col = tid & 63;                                         \
            const int rh  = tid >> 6;                                         \
            _Pragma("unroll")                                                 \
            for (int pass = 0; pass < 2; pass++) {                            \
                const int row = pass * 8 + rh;                                \
                float osum = 0.f, lsum = 0.f;                                 \
                _Pragma("unroll")                                             \
                for (int w2 = 0; w2 < 8; w2++) {                              \
                    osum += opart[w2][row][col];                              \
                    lsum += lpart[w2][row];                                   \
                }                                                             \
                out[((size_t)b * T + (ROWBASE) + row) * HD + col] = osum / lsum; \
            }                                                                 \
        }                                                                     \
        __syncthreads();                                                      \
    }

    DEPOSIT_MERGE(oA0, lrA0, rbA)
    DEPOSIT_MERGE(oA1, lrA1, rbA + 16)
    DEPOSIT_MERGE(oB0, lrB0, rbB)
    DEPOSIT_MERGE(oB1, lrB1, rbB + 16)
#undef DEPOSIT_MERGE
}

// ---------------------------------------------------------------------------
extern "C" void kernel_launch(void* const* d_in, const int* in_sizes, int n_in,
                              void* d_out, int out_size, void* d_ws, size_t ws_size,
                              hipStream_t stream) {
    const float* x  = (const float*)d_in[0];
    const float* Wq = (const float*)d_in[1];
    const float* Wk = (const float*)d_in[2];
    const float* Wv = (const float*)d_in[3];
    float* out = (float*)d_out;

    bf16_t* ws  = (bf16_t*)d_ws;
    bf16_t* WTt = ws;                          // tiled [192][1024]
    bf16_t* qtl = WTt + (size_t)192 * E;       // tiled [BT][HD]
    bf16_t* ktl = qtl + (size_t)BT * HD;       // tiled [BT][HD]
    bf16_t* vtl = ktl + (size_t)BT * HD;       // tiled [BATCH][HD][T]

    prep_w<<<96, 256, 0, stream>>>(Wq, Wk, Wv, WTt);
    qkv_proj<<<512, 512, 0, stream>>>(x, WTt, qtl, ktl, vtl);
    attn<<<256, 512, 0, stream>>>(qtl, ktl, vtl, out);
}

// Round 16
// 119.018 us; speedup vs baseline: 1.0273x; 1.0273x over previous
//
#include <hip/hip_runtime.h>
#include <hip/hip_bf16.h>
#include <math.h>

// Problem constants
#define BATCH 8
#define T 2048
#define E 1024
#define HD 64
#define BT (BATCH * T)  // 16384

typedef __bf16 bf16_t;
typedef bf16_t bf16x4 __attribute__((ext_vector_type(4)));
typedef bf16_t bf16x8 __attribute__((ext_vector_type(8)));
typedef float f32x4 __attribute__((ext_vector_type(4)));

#define MFMA(a, b, c) __builtin_amdgcn_mfma_f32_16x16x32_bf16((a), (b), (c), 0, 0, 0)

// q scale folded into Wq at prep; softmax in exp2 domain (no-max: scores
// sigma~1.44, f32 exp2 overflows at 127 ~ 88 sigma -- unreachable).
#define QSCALE (0.125f * 1.44269504088896340736f)

// Tiled layout for all MFMA operands: idx(r,c) over [R][C] =
//   (r>>4)*(16*C) + (c>>3)*128 + (r&15)*8 + (c&7)
// => a wave fragment load is ONE contiguous 1KB read: base + c0*16 + lane*8.

// ---------------------------------------------------------------------------
// Kernel 0: prep weights into tiled WT[192 n][1024 k] = W[k][n] (*QSCALE for q).
// ---------------------------------------------------------------------------
__global__ __launch_bounds__(256) void prep_w(const float* __restrict__ Wq,
                                              const float* __restrict__ Wk,
                                              const float* __restrict__ Wv,
                                              bf16_t* __restrict__ WTt) {
    const int nt  = blockIdx.x >> 3;          // 0..11
    const int kc0 = (blockIdx.x & 7) * 128;
    const int tid = threadIdx.x;
    const int l16 = tid & 15;
    const int k8  = (kc0 >> 3) + (tid >> 4);  // 0..127
    const int n   = nt * 16 + l16;
    const int m   = n >> 6;                   // block-uniform: 0=q,1=k,2=v
    const int col = n & 63;
    const float* W = (m == 0) ? Wq : (m == 1) ? Wk : Wv;
    const float scale = (m == 0) ? QSCALE : 1.0f;
    bf16x8 o;
#pragma unroll
    for (int j = 0; j < 8; j++) {
        o[j] = (bf16_t)(W[(size_t)(k8 * 8 + j) * HD + col] * scale);
    }
    *reinterpret_cast<bf16x8*>(WTt + (size_t)nt * 16384 + k8 * 128 + l16 * 8) = o;
}

// ---------------------------------------------------------------------------
// Kernel 1: QKV projection — EXACT R11 (best verified: coalesced stage +
// K-split waves at 256 blocks x 64 rows -> B-traffic 98MB, qkv ~23us).
// [Design matrix closed: R9 glds/1024blk=27, R14 reg/512blk=23-neutral,
// R15 glds/512blk=26-regress. glds+64row impossible (f32 LDS > 160KB).]
// ---------------------------------------------------------------------------
__global__ __launch_bounds__(512, 2) void qkv_proj(
    const float* __restrict__ x,     // [BT][E] f32
    const bf16_t* __restrict__ WTt,  // tiled [192][E]
    bf16_t* __restrict__ qt,         // tiled [BT][HD] (scaled)
    bf16_t* __restrict__ kt,         // tiled [BT][HD]
    bf16_t* __restrict__ vt)         // tiled per batch [HD][T]
{
    __shared__ __align__(16) bf16_t xb[64][1024];   // 128 KB bf16

    const int tid  = threadIdx.x;
    const int w    = tid >> 6;           // wave 0..7
    const int lane = tid & 63;
    const int l16  = lane & 15;
    const int quad = lane >> 4;
    const int wk   = w >> 2;             // K half: [wk*512, +512)
    const int wc   = w & 3;              // col tiles 3wc..3wc+2
    const int rowbase0 = blockIdx.x * 64;

    // ---- stage: 256 instrs of contiguous 1KB; instr gi covers row gi>>2,
    // quarter gi&3; lane l takes 16B at l*16. 4 rounds of 8 loads/thread. ----
    {
#pragma unroll
        for (int rd = 0; rd < 4; rd++) {
            f32x4 v[8];
#pragma unroll
            for (int j = 0; j < 8; j++) {
                const int gi = w * 32 + rd * 8 + j;
                const int r  = gi >> 2;
                const int q  = gi & 3;
                v[j] = *reinterpret_cast<const f32x4*>(
                    x + (size_t)(rowbase0 + r) * E + q * 256 + lane * 4);
            }
            __builtin_amdgcn_sched_barrier(0);   // pin: 8 loads issue first
#pragma unroll
            for (int j = 0; j < 8; j++) {
                const int gi = w * 32 + rd * 8 + j;
                const int r  = gi >> 2;
                const int q  = gi & 3;
                bf16x4 w4;
#pragma unroll
                for (int u = 0; u < 4; u++) w4[u] = (bf16_t)v[j][u];
                char* base = reinterpret_cast<char*>(&xb[r][0]);
                const int off = (q * 512 + lane * 8) ^ ((r & 7) << 4);
                *reinterpret_cast<bf16x4*>(base + off) = w4;
            }
        }
    }
    __syncthreads();   // strip resident

    // ---- compute: 8 kc-iters over own K-half; B read once per block ----
    const bf16_t* Bb = WTt + (size_t)(wc * 3) * 16384 + lane * 8;
    f32x4 acc[4][3] = {};

    for (int kc8 = 0; kc8 < 8; kc8++) {
        const int kk = wk * 512 + kc8 * 64;
        bf16x8 bf[2][3];
#pragma unroll
        for (int ks = 0; ks < 2; ks++)
#pragma unroll
            for (int tc = 0; tc < 3; tc++)
                bf[ks][tc] = *reinterpret_cast<const bf16x8*>(
                    Bb + (size_t)tc * 16384 + (kk + ks * 32) * 16);

#pragma unroll
        for (int g = 0; g < 4; g++) {
            const int row = g * 16 + l16;
            const int swz = (row & 7) << 4;
            const char* rb = reinterpret_cast<const char*>(&xb[row][0]);
            const bf16x8 a0 = *reinterpret_cast<const bf16x8*>(
                rb + ((kk * 2 + quad * 16) ^ swz));
            const bf16x8 a1 = *reinterpret_cast<const bf16x8*>(
                rb + ((kk * 2 + 64 + quad * 16) ^ swz));
#pragma unroll
            for (int tc = 0; tc < 3; tc++) acc[g][tc] = MFMA(a0, bf[0][tc], acc[g][tc]);
#pragma unroll
            for (int tc = 0; tc < 3; tc++) acc[g][tc] = MFMA(a1, bf[1][tc], acc[g][tc]);
        }
    }

    // ---- merge K-half partials via LDS (xb reusable after sync) ----
    __syncthreads();
    float* pbuf = reinterpret_cast<float*>(&xb[0][0]);   // 48 KB used
    if (wk == 1) {
#pragma unroll
        for (int g = 0; g < 4; g++)
#pragma unroll
            for (int tc = 0; tc < 3; tc++) {
                const int idx = (((wc * 4 + g) * 3) + tc) * 256 + lane * 4;
                *reinterpret_cast<f32x4*>(pbuf + idx) = acc[g][tc];
            }
    }
    __syncthreads();
    if (wk == 0) {
#pragma unroll
        for (int g = 0; g < 4; g++)
#pragma unroll
            for (int tc = 0; tc < 3; tc++) {
                const int idx = (((wc * 4 + g) * 3) + tc) * 256 + lane * 4;
                acc[g][tc] += *reinterpret_cast<const f32x4*>(pbuf + idx);
            }

        // ---- epilogue (R4/R9/R10/R11-verified mapping), per row group ----
#pragma unroll
        for (int g = 0; g < 4; g++) {
            const int rowbase = rowbase0 + g * 16;
#pragma unroll
            for (int tc = 0; tc < 3; tc++) {
                const int n0  = wc * 48 + tc * 16;
                const int m   = n0 >> 6;     // wave-uniform per tc: 0=q,1=k,2=v
                const int tcg = (n0 & 63) >> 4;
                if (m < 2) {
                    bf16_t* dst = (m == 0) ? qt : kt;
                    const size_t o0 = (size_t)(rowbase >> 4) * 1024 +
                                      (size_t)(tcg * 2 + (l16 >> 3)) * 128 + (l16 & 7);
#pragma unroll
                    for (int r = 0; r < 4; r++) {
                        dst[o0 + (quad * 4 + r) * 8] = (bf16_t)acc[g][tc][r];
                    }
                } else {
                    const int b_    = rowbase >> 11;
                    const int tbase = rowbase & (T - 1);
                    const size_t o0 = (size_t)b_ * 131072 +
                                      (size_t)((tbase >> 3) + (quad >> 1)) * 128 +
                                      l16 * 8 + (quad & 1) * 4 + (size_t)tcg * 32768;
                    bf16x4 pv;
#pragma unroll
                    for (int r = 0; r < 4; r++) pv[r] = (bf16_t)acc[g][tc][r];
                    *reinterpret_cast<bf16x4*>(vt + o0) = pv;
                }
            }
        }
    }
}

// ---------------------------------------------------------------------------
// Kernel 2: causal flash attention — R13 supertile/task-queue version,
// byte-identical (verified at 119.36).
// ---------------------------------------------------------------------------
__global__ __launch_bounds__(512, 2) void attn(
    const bf16_t* __restrict__ qtl,  // tiled [BT][HD], pre-scaled
    const bf16_t* __restrict__ ktl,  // tiled [BT][HD]
    const bf16_t* __restrict__ vtl,  // tiled per batch [HD][T]
    float* __restrict__ out)         // [BT][HD] f32 row-major
{
    __shared__ __align__(16) bf16_t plds[8][2][16][40];
    __shared__ float opart[8][16][66];
    __shared__ float lpart[8][16];

    const int tid  = threadIdx.x;
    const int wave = tid >> 6;
    const int lane = tid & 63;
    const int l16  = lane & 15;
    const int quad = lane >> 4;

    const int b  = blockIdx.x >> 5;      // 0..7
    const int pp = blockIdx.x & 31;      // 0..31
    const int rbA = pp * 32;             // supertile A rows
    const int rbB = (63 - pp) * 32;      // supertile B rows
    const int nchA = pp + 1;             // chunks for A; B has 64-pp; total 65

    const bf16_t* Kb = ktl + (size_t)b * T * 64 + lane * 8;
    const bf16_t* Vb = vtl + (size_t)b * 131072 + lane * 8;
    const bf16_t* QbA = qtl + (size_t)((b * T + rbA) >> 4) * 1024 + lane * 8;
    const bf16_t* QbB = qtl + (size_t)((b * T + rbB) >> 4) * 1024 + lane * 8;

    // Q fragments: per supertile, 2 subtiles x {K0-31, K32-63}
    const bf16x8 qA0l = *reinterpret_cast<const bf16x8*>(QbA);
    const bf16x8 qA0h = *reinterpret_cast<const bf16x8*>(QbA + 512);
    const bf16x8 qA1l = *reinterpret_cast<const bf16x8*>(QbA + 1024);
    const bf16x8 qA1h = *reinterpret_cast<const bf16x8*>(QbA + 1536);
    const bf16x8 qB0l = *reinterpret_cast<const bf16x8*>(QbB);
    const bf16x8 qB0h = *reinterpret_cast<const bf16x8*>(QbB + 512);
    const bf16x8 qB1l = *reinterpret_cast<const bf16x8*>(QbB + 1024);
    const bf16x8 qB1h = *reinterpret_cast<const bf16x8*>(QbB + 1536);

    f32x4 oA0[4] = {}, oA1[4] = {}, oB0[4] = {}, oB1[4] = {};
    f32x4 lrA0 = {}, lrA1 = {}, lrB0 = {}, lrB1 = {};

    // preload K for first task
    int k0;
    bf16x8 kfa0, kfb0, kfa1, kfb1;
    {
        const int tf = wave;
        const int cf = (tf < nchA) ? tf : tf - nchA;
        kfa0 = *reinterpret_cast<const bf16x8*>(Kb + cf * 32 * 64);
        kfb0 = *reinterpret_cast<const bf16x8*>(Kb + cf * 32 * 64 + 512);
        kfa1 = *reinterpret_cast<const bf16x8*>(Kb + cf * 32 * 64 + 1024);
        kfb1 = *reinterpret_cast<const bf16x8*>(Kb + cf * 32 * 64 + 1536);
    }

#define ATTN_STEP(QL0, QH0, QL1, QH1, RB_, O0, O1, LR0, LR1)                  \
    {                                                                         \
        f32x4 s0l = {}, s0h = {}, s1l = {}, s1h = {};                         \
        s0l = MFMA(QL0, kfa0, s0l);  s0l = MFMA(QH0, kfb0, s0l);              \
        s0h = MFMA(QL0, kfa1, s0h);  s0h = MFMA(QH0, kfb1, s0h);              \
        s1l = MFMA(QL1, kfa0, s1l);  s1l = MFMA(QH1, kfb0, s1l);              \
        s1h = MFMA(QL1, kfa1, s1h);  s1h = MFMA(QH1, kfb1, s1h);              \
        if (k0 + 31 > (RB_)) {                                                \
            const int row = (RB_) + quad * 4;                                 \
            _Pragma("unroll")                                                 \
            for (int r = 0; r < 4; r++) {                                     \
                if (k0 + l16 > row + r)      s0l[r] = -INFINITY;              \
                if (k0 + 16 + l16 > row + r) s0h[r] = -INFINITY;              \
            }                                                                 \
        }                                                                     \
        if (k0 + 31 > (RB_) + 16) {                                           \
            const int row = (RB_) + 16 + quad * 4;                            \
            _Pragma("unroll")                                                 \
            for (int r = 0; r < 4; r++) {                                     \
                if (k0 + l16 > row + r)      s1l[r] = -INFINITY;              \
                if (k0 + 16 + l16 > row + r) s1h[r] = -INFINITY;              \
            }                                                                 \
        }                                                                     \
        _Pragma("unroll")                                                     \
        for (int r = 0; r < 4; r++) {                                         \
            const float p00 = exp2f(s0l[r]);                                  \
            const float p01 = exp2f(s0h[r]);                                  \
            (LR0)[r] += p00 + p01;                                            \
            plds[wave][0][quad * 4 + r][l16]      = (bf16_t)p00;              \
            plds[wave][0][quad * 4 + r][16 + l16] = (bf16_t)p01;              \
            const float p10 = exp2f(s1l[r]);                                  \
            const float p11 = exp2f(s1h[r]);                                  \
            (LR1)[r] += p10 + p11;                                            \
            plds[wave][1][quad * 4 + r][l16]      = (bf16_t)p10;              \
            plds[wave][1][quad * 4 + r][16 + l16] = (bf16_t)p11;              \
        }                                                                     \
        const bf16x8 pf0 = *reinterpret_cast<const bf16x8*>(                  \
            &plds[wave][0][l16][quad * 8]);                                   \
        const bf16x8 pf1 = *reinterpret_cast<const bf16x8*>(                  \
            &plds[wave][1][l16][quad * 8]);                                   \
        (O0)[0] = MFMA(pf0, vf0, (O0)[0]);  (O1)[0] = MFMA(pf1, vf0, (O1)[0]);\
        (O0)[1] = MFMA(pf0, vf1, (O0)[1]);  (O1)[1] = MFMA(pf1, vf1, (O1)[1]);\
        (O0)[2] = MFMA(pf0, vf2, (O0)[2]);  (O1)[2] = MFMA(pf1, vf2, (O1)[2]);\
        (O0)[3] = MFMA(pf0, vf3, (O0)[3]);  (O1)[3] = MFMA(pf1, vf3, (O1)[3]);\
    }

    for (int task = wave; task < 65; task += 8) {
        const bool isA = task < nchA;
        const int  c   = isA ? task : task - nchA;
        k0 = c * 32;

        // V for this chunk first (consumed this iter)...
        const bf16x8 vf0 = *reinterpret_cast<const bf16x8*>(Vb + k0 * 16);
        const bf16x8 vf1 = *reinterpret_cast<const bf16x8*>(Vb + k0 * 16 + 32768);
        const bf16x8 vf2 = *reinterpret_cast<const bf16x8*>(Vb + k0 * 16 + 65536);
        const bf16x8 vf3 = *reinterpret_cast<const bf16x8*>(Vb + k0 * 16 + 98304);
        // ...then next-task K prefetch (newer: never drained by this iter)
        const int tn = (task + 8 < 65) ? task + 8 : task;
        const int cn = (tn < nchA) ? tn : tn - nchA;
        const int kn = cn * 32;
        const bf16x8 nkfa0 = *reinterpret_cast<const bf16x8*>(Kb + kn * 64);
        const bf16x8 nkfb0 = *reinterpret_cast<const bf16x8*>(Kb + kn * 64 + 512);
        const bf16x8 nkfa1 = *reinterpret_cast<const bf16x8*>(Kb + kn * 64 + 1024);
        const bf16x8 nkfb1 = *reinterpret_cast<const bf16x8*>(Kb + kn * 64 + 1536);

        if (isA) {
            ATTN_STEP(qA0l, qA0h, qA1l, qA1h, rbA, oA0, oA1, lrA0, lrA1)
        } else {
            ATTN_STEP(qB0l, qB0h, qB1l, qB1h, rbB, oB0, oB1, lrB0, lrB1)
        }

        kfa0 = nkfa0; kfb0 = nkfb0; kfa1 = nkfa1; kfb1 = nkfb1;
    }
#undef ATTN_STEP

    // ---- 4-stage deposit + merge (reuses opart/lpart each stage) ----
#define DEPOSIT_MERGE(OX, LRX, ROWBASE)                                       \
    {                                                                         \
        _Pragma("unroll")                                                     \
        for (int r = 0; r < 4; r++) {                                         \
            float l = (LRX)[r];                                               \
            l += __shfl_xor(l, 1); l += __shfl_xor(l, 2);                     \
            l += __shfl_xor(l, 4); l += __shfl_xor(l, 8);                     \
            if (l16 == 0) lpart[wave][quad * 4 + r] = l;                      \
            _Pragma("unroll")                                                 \
            for (int nb = 0; nb < 4; nb++)                                    \
                opart[wave][quad * 4 + r][nb * 16 + l16] = (OX)[nb][r];       \
        }                                                                     \
        __syncthreads();                                                      \
        {                                                                     \
            const int col = tid & 63;                                         \
            const int rh  = tid >> 6;                                         \
            _Pragma("unroll")                                                 \
            for (int pass = 0; pass < 2; pass++) {                            \
                const int row = pass * 8 + rh;                                \
                float osum = 0.f, lsum = 0.f;                                 \
                _Pragma("unroll")                                             \
                for (int w2 = 0; w2 < 8; w2++) {                              \
                    osum += opart[w2][row][col];                              \
                    lsum += lpart[w2][row];                                   \
                }                                                             \
                out[((size_t)b * T + (ROWBASE) + row) * HD + col] = osum / lsum; \
            }                                                                 \
        }                                                                     \
        __syncthreads();                                                      \
    }

    DEPOSIT_MERGE(oA0, lrA0, rbA)
    DEPOSIT_MERGE(oA1, lrA1, rbA + 16)
    DEPOSIT_MERGE(oB0, lrB0, rbB)
    DEPOSIT_MERGE(oB1, lrB1, rbB + 16)
#undef DEPOSIT_MERGE
}

// ---------------------------------------------------------------------------
extern "C" void kernel_launch(void* const* d_in, const int* in_sizes, int n_in,
                              void* d_out, int out_size, void* d_ws, size_t ws_size,
                              hipStream_t stream) {
    const float* x  = (const float*)d_in[0];
    const float* Wq = (const float*)d_in[1];
    const float* Wk = (const float*)d_in[2];
    const float* Wv = (const float*)d_in[3];
    float* out = (float*)d_out;

    bf16_t* ws  = (bf16_t*)d_ws;
    bf16_t* WTt = ws;                          // tiled [192][1024]
    bf16_t* qtl = WTt + (size_t)192 * E;       // tiled [BT][HD]
    bf16_t* ktl = qtl + (size_t)BT * HD;       // tiled [BT][HD]
    bf16_t* vtl = ktl + (size_t)BT * HD;       // tiled [BATCH][HD][T]

    prep_w<<<96, 256, 0, stream>>>(Wq, Wk, Wv, WTt);
    qkv_proj<<<256, 512, 0, stream>>>(x, WTt, qtl, ktl, vtl);
    attn<<<256, 512, 0, stream>>>(qtl, ktl, vtl, out);
}